// Round 1
// baseline (352.091 us; speedup 1.0000x reference)
//
#include <hip/hip_runtime.h>

#define HH 192
#define WW 192
#define CC 64
#define BB 8
#define SH 8
#define HWSZ (HH*WW)
#define TAU 0.1f

// ---------------- Kernel A: conv3x3 (64->8, SAME, zero pad) + exact GELU ----------------
__global__ __launch_bounds__(256) void conv1_gelu_kernel(
    const float* __restrict__ x, const float* __restrict__ w1, float* __restrict__ h)
{
    __shared__ float tile[18][20];   // 18x18 halo tile, padded stride to soften bank conflicts
    const int t  = threadIdx.x;
    const int tx = t & 15;
    const int ty = t >> 4;
    const int bx = blockIdx.x * 16;
    const int by = blockIdx.y * 16;
    const int b  = blockIdx.z;

    float acc[SH];
#pragma unroll
    for (int i = 0; i < SH; i++) acc[i] = 0.f;

    for (int c = 0; c < CC; c++) {
        const float* xp = x + ((size_t)(b * CC + c)) * HWSZ;
        // cooperative load of 18x18 = 324 elements with zero padding at borders
#pragma unroll
        for (int e = 0; e < 2; e++) {
            int idx = t + e * 256;
            if (idx < 324) {
                int iy = idx / 18;
                int ix = idx - iy * 18;
                int gy = by + iy - 1;
                int gx = bx + ix - 1;
                float v = 0.f;
                if (gy >= 0 && gy < HH && gx >= 0 && gx < WW) v = xp[gy * WW + gx];
                tile[iy][ix] = v;
            }
        }
        __syncthreads();

        const float t00 = tile[ty + 0][tx + 0], t01 = tile[ty + 0][tx + 1], t02 = tile[ty + 0][tx + 2];
        const float t10 = tile[ty + 1][tx + 0], t11 = tile[ty + 1][tx + 1], t12 = tile[ty + 1][tx + 2];
        const float t20 = tile[ty + 2][tx + 0], t21 = tile[ty + 2][tx + 1], t22 = tile[ty + 2][tx + 2];

#pragma unroll
        for (int sh = 0; sh < SH; sh++) {
            const float* w = w1 + ((size_t)sh * CC + c) * 9;   // uniform address -> scalar loads
            acc[sh] += t00 * w[0] + t01 * w[1] + t02 * w[2]
                     + t10 * w[3] + t11 * w[4] + t12 * w[5]
                     + t20 * w[6] + t21 * w[7] + t22 * w[8];
        }
        __syncthreads();
    }

    const int y = by + ty, xo = bx + tx;
#pragma unroll
    for (int sh = 0; sh < SH; sh++) {
        float v = acc[sh];
        float g = 0.5f * v * (1.f + erff(v * 0.70710678118654752f));  // exact GELU
        h[((size_t)(b * SH + sh)) * HWSZ + y * WW + xo] = g;
    }
}

// ---------------- Kernel B: 1x1 conv coeffs + softplus/clip + 4 bilinear samples ----------------
__device__ __forceinline__ float bilin(const float* __restrict__ img, float px, float py)
{
    px = fminf(fmaxf(px, 0.f), (float)(WW - 1));
    py = fminf(fmaxf(py, 0.f), (float)(HH - 1));
    float x0f = floorf(px), y0f = floorf(py);
    float wx = px - x0f, wy = py - y0f;
    int x0 = (int)x0f, y0 = (int)y0f;
    int x1 = min(x0 + 1, WW - 1), y1 = min(y0 + 1, HH - 1);
    const float* r0 = img + y0 * WW;
    const float* r1 = img + y1 * WW;
    float v00 = r0[x0], v01 = r0[x1], v10 = r1[x0], v11 = r1[x1];
    float top = v00 * (1.f - wx) + v01 * wx;
    float bot = v10 * (1.f - wx) + v11 * wx;
    return top * (1.f - wy) + bot * wy;
}

__global__ __launch_bounds__(256) void coeff_sample_kernel(
    const float* __restrict__ x, const float* __restrict__ hbuf,
    const float* __restrict__ w2, const float* __restrict__ b2,
    const float* __restrict__ log_scale, float* __restrict__ out)
{
    const int t  = threadIdx.x;
    const int tx = t & 15;
    const int ty = t >> 4;
    const int xo = blockIdx.x * 16 + tx;
    const int y  = blockIdx.y * 16 + ty;
    const int bc = blockIdx.z;           // b*64 + c
    const int c  = bc & 63;

    // h[b, 0..7, y, x]
    const float* hp = hbuf + ((size_t)(bc >> 6) * SH) * HWSZ + y * WW + xo;
    float hk[SH];
#pragma unroll
    for (int k = 0; k < SH; k++) hk[k] = hp[k * HWSZ];

    const int c4 = c * 4;
    float coeff[4];
#pragma unroll
    for (int j = 0; j < 4; j++) {
        const float* wr = w2 + (size_t)(c4 + j) * SH;  // uniform per block
        float s = b2[c4 + j];
#pragma unroll
        for (int k = 0; k < SH; k++) s += hk[k] * wr[k];
        coeff[j] = s;
    }

    // softplus (stable, matches logaddexp(x,0))
    float a  = fmaxf(coeff[0], 0.f) + log1pf(expf(-fabsf(coeff[0])));
    float s  = sqrtf(a * TAU + 1e-8f);
    float dx = coeff[1] * TAU;
    float dy = coeff[2] * TAU;
    float cc = fminf(fmaxf(coeff[3], -5.f), 5.f);

    const float* img = x + (size_t)bc * HWSZ;
    const float xf = (float)xo, yf = (float)y;
    // (gx+1)*0.5*(W-1) with gx = -1 + 2*x/(W-1) + shift  ==  x + shift*95.5
    const float px0 = xf + dx * 95.5f;
    const float py0 = yf + dy * 95.5f;
    const float sp  = s * 95.5f;

    float u = bilin(img, px0 + sp, py0)
            + bilin(img, px0 - sp, py0)
            + bilin(img, px0, py0 + sp)
            + bilin(img, px0, py0 - sp);

    float xv = img[y * WW + xo];
    out[(size_t)bc * HWSZ + y * WW + xo] = expf(log_scale[0]) * (0.25f * u + TAU * cc * xv);
}

extern "C" void kernel_launch(void* const* d_in, const int* in_sizes, int n_in,
                              void* d_out, int out_size, void* d_ws, size_t ws_size,
                              hipStream_t stream)
{
    const float* x   = (const float*)d_in[0];
    const float* w1  = (const float*)d_in[1];
    const float* w2  = (const float*)d_in[2];
    const float* b2  = (const float*)d_in[3];
    const float* ls  = (const float*)d_in[4];
    float* out = (float*)d_out;
    float* h   = (float*)d_ws;   // B*SH*H*W floats = 9.4 MB

    dim3 blk(256);
    dim3 g1(WW / 16, HH / 16, BB);
    conv1_gelu_kernel<<<g1, blk, 0, stream>>>(x, w1, h);

    dim3 g2(WW / 16, HH / 16, BB * CC);
    coeff_sample_kernel<<<g2, blk, 0, stream>>>(x, h, w2, b2, ls, out);
}

// Round 2
// 342.884 us; speedup vs baseline: 1.0269x; 1.0269x over previous
//
#include <hip/hip_runtime.h>

#define HH 192
#define WW 192
#define CC 64
#define BB 8
#define SH 8
#define HWSZ (HH*WW)
#define TAU 0.1f

// ---------------- Kernel A: conv3x3 (64->8, SAME) + exact GELU ----------------
// 32x16 output tile, 256 threads, each thread computes a horizontal 2x1 pair,
// channels processed in chunks of 4 staged in LDS.
#define AX 32
#define AY 16
#define HALOX 34
#define HALOY 18
#define PADX 37              // odd pad -> <=2-way LDS bank aliasing (free)
#define CCH 4
#define NELTS (CCH*HALOY*HALOX)   // 2448
#define NLOAD 10                  // ceil(2448/256)

__global__ __launch_bounds__(256) void conv1_gelu_kernel(
    const float* __restrict__ x, const float* __restrict__ w1, float* __restrict__ h)
{
    __shared__ float tile[CCH][HALOY][PADX];
    const int t  = threadIdx.x;
    const int bx = blockIdx.x * AX;
    const int by = blockIdx.y * AY;
    const int b  = blockIdx.z;

    // Round-invariant load slots: idx -> (c_local, iy, ix) decomposition done ONCE.
    int  lds_off[NLOAD];
    int  g_off[NLOAD];
    bool inr[NLOAD];     // idx < NELTS  (LDS write enable)
    bool ldok[NLOAD];    // in-image     (global load enable; else write zero)
#pragma unroll
    for (int i = 0; i < NLOAD; i++) {
        int idx = t + i * 256;
        bool v = idx < NELTS;
        int cl  = idx / (HALOY * HALOX);
        int rem = idx - cl * (HALOY * HALOX);
        int iy  = rem / HALOX;
        int ix  = rem - iy * HALOX;
        int gy  = by + iy - 1;
        int gx  = bx + ix - 1;
        bool ok = v && (gy >= 0) && (gy < HH) && (gx >= 0) && (gx < WW);
        inr[i]     = v;
        ldok[i]    = ok;
        lds_off[i] = (cl * HALOY + iy) * PADX + ix;
        g_off[i]   = ok ? (cl * HWSZ + gy * WW + gx) : 0;
    }

    const int tx = t & 15, ty = t >> 4;
    const int ox = tx * 2;
    const int oy = ty;

    float acc[SH][2];
#pragma unroll
    for (int sh = 0; sh < SH; sh++) { acc[sh][0] = 0.f; acc[sh][1] = 0.f; }

    float* tile0 = &tile[0][0][0];

    for (int r = 0; r < CC / CCH; r++) {
        const int c0 = r * CCH;
        const float* xp = x + ((size_t)(b * CC + c0)) * HWSZ;
#pragma unroll
        for (int i = 0; i < NLOAD; i++) {
            float val = 0.f;
            if (ldok[i]) val = xp[g_off[i]];
            if (inr[i])  tile0[lds_off[i]] = val;
        }
        __syncthreads();

#pragma unroll
        for (int cl = 0; cl < CCH; cl++) {
            float win[3][4];
#pragma unroll
            for (int i = 0; i < 3; i++)
#pragma unroll
                for (int j = 0; j < 4; j++)
                    win[i][j] = tile[cl][oy + i][ox + j];

#pragma unroll
            for (int sh = 0; sh < SH; sh++) {
                const float* ws = w1 + ((size_t)sh * CC + (c0 + cl)) * 9;  // uniform -> s_load
                float a0 = acc[sh][0], a1 = acc[sh][1];
                a0 = fmaf(win[0][0], ws[0], a0); a1 = fmaf(win[0][1], ws[0], a1);
                a0 = fmaf(win[0][1], ws[1], a0); a1 = fmaf(win[0][2], ws[1], a1);
                a0 = fmaf(win[0][2], ws[2], a0); a1 = fmaf(win[0][3], ws[2], a1);
                a0 = fmaf(win[1][0], ws[3], a0); a1 = fmaf(win[1][1], ws[3], a1);
                a0 = fmaf(win[1][1], ws[4], a0); a1 = fmaf(win[1][2], ws[4], a1);
                a0 = fmaf(win[1][2], ws[5], a0); a1 = fmaf(win[1][3], ws[5], a1);
                a0 = fmaf(win[2][0], ws[6], a0); a1 = fmaf(win[2][1], ws[6], a1);
                a0 = fmaf(win[2][1], ws[7], a0); a1 = fmaf(win[2][2], ws[7], a1);
                a0 = fmaf(win[2][2], ws[8], a0); a1 = fmaf(win[2][3], ws[8], a1);
                acc[sh][0] = a0; acc[sh][1] = a1;
            }
        }
        __syncthreads();
    }

    const int y = by + oy, xo = bx + ox;
#pragma unroll
    for (int sh = 0; sh < SH; sh++) {
        float v0 = acc[sh][0], v1 = acc[sh][1];
        float2 g;
        g.x = 0.5f * v0 * (1.f + erff(v0 * 0.70710678118654752f));
        g.y = 0.5f * v1 * (1.f + erff(v1 * 0.70710678118654752f));
        *reinterpret_cast<float2*>(&h[((size_t)(b * SH + sh)) * HWSZ + y * WW + xo]) = g;
    }
}

// ---------------- Kernel B: 1x1 conv coeffs + softplus/clip + 4 bilinear samples ----------------
__device__ __forceinline__ float sample_x(const float* __restrict__ img,
                                          int r0, int r1, float wy, float px)
{
    px = fminf(fmaxf(px, 0.f), 191.f);
    float x0f = floorf(px);
    float wx  = px - x0f;
    int x0 = (int)x0f;
    int x1 = x0 + ((x0 < WW - 1) ? 1 : 0);
    float v00 = img[r0 + x0], v01 = img[r0 + x1];
    float v10 = img[r1 + x0], v11 = img[r1 + x1];
    float top = fmaf(wx, v01 - v00, v00);
    float bot = fmaf(wx, v11 - v10, v10);
    return fmaf(wy, bot - top, top);
}

__device__ __forceinline__ float sample_y(const float* __restrict__ img,
                                          int x0, int x1, float wx, float py)
{
    py = fminf(fmaxf(py, 0.f), 191.f);
    float y0f = floorf(py);
    float wy  = py - y0f;
    int y0 = (int)y0f;
    int r0 = y0 * WW;
    int r1 = r0 + ((y0 < HH - 1) ? WW : 0);
    float v00 = img[r0 + x0], v01 = img[r0 + x1];
    float v10 = img[r1 + x0], v11 = img[r1 + x1];
    float top = fmaf(wx, v01 - v00, v00);
    float bot = fmaf(wx, v11 - v10, v10);
    return fmaf(wy, bot - top, top);
}

__global__ __launch_bounds__(256) void coeff_sample_kernel(
    const float* __restrict__ x, const float* __restrict__ hbuf,
    const float* __restrict__ w2, const float* __restrict__ b2,
    const float* __restrict__ log_scale, float* __restrict__ out)
{
    const int t  = threadIdx.x;
    const int tx = t & 15;
    const int ty = t >> 4;
    const int xo = blockIdx.x * 16 + tx;
    const int y  = blockIdx.y * 16 + ty;
    const int bc = blockIdx.z;           // b*64 + c
    const int c  = bc & 63;
    const int pix = y * WW + xo;

    const float* hp = hbuf + ((size_t)(bc >> 6) * SH) * HWSZ + pix;
    float hk[SH];
#pragma unroll
    for (int k = 0; k < SH; k++) hk[k] = hp[k * HWSZ];

    const int c4 = c * 4;
    float coeff[4];
#pragma unroll
    for (int j = 0; j < 4; j++) {
        const float* wr = w2 + (size_t)(c4 + j) * SH;  // uniform per block
        float s = b2[c4 + j];
#pragma unroll
        for (int k = 0; k < SH; k++) s = fmaf(hk[k], wr[k], s);
        coeff[j] = s;
    }

    // softplus (stable): max(z,0) + log(1+exp(-|z|)); fast intrinsics (rel err ~1e-6)
    float z  = coeff[0];
    float a  = fmaxf(z, 0.f) + __logf(1.f + __expf(-fabsf(z)));
    float s  = sqrtf(fmaf(a, TAU, 1e-8f));
    float dx = coeff[1] * TAU;
    float dy = coeff[2] * TAU;
    float cc = fminf(fmaxf(coeff[3], -5.f), 5.f);

    const float* img = x + (size_t)bc * HWSZ;
    // grid->pixel: px = x + shift*95.5 exactly (W-1)/2 = 95.5
    const float px0 = (float)xo + dx * 95.5f;
    const float py0 = (float)y  + dy * 95.5f;
    const float sp  = s * 95.5f;

    float u;
    {   // u_px + u_nx share the y interpolation state
        float py  = fminf(fmaxf(py0, 0.f), 191.f);
        float y0f = floorf(py);
        float wy  = py - y0f;
        int y0 = (int)y0f;
        int r0 = y0 * WW;
        int r1 = r0 + ((y0 < HH - 1) ? WW : 0);
        u = sample_x(img, r0, r1, wy, px0 + sp)
          + sample_x(img, r0, r1, wy, px0 - sp);
    }
    {   // u_py + u_ny share the x interpolation state
        float px  = fminf(fmaxf(px0, 0.f), 191.f);
        float x0f = floorf(px);
        float wx  = px - x0f;
        int x0 = (int)x0f;
        int x1 = x0 + ((x0 < WW - 1) ? 1 : 0);
        u += sample_y(img, x0, x1, wx, py0 + sp)
           + sample_y(img, x0, x1, wx, py0 - sp);
    }

    float xv    = img[pix];
    float scale = __expf(log_scale[0]);
    out[(size_t)bc * HWSZ + pix] = scale * fmaf(0.25f, u, TAU * cc * xv);
}

extern "C" void kernel_launch(void* const* d_in, const int* in_sizes, int n_in,
                              void* d_out, int out_size, void* d_ws, size_t ws_size,
                              hipStream_t stream)
{
    const float* x   = (const float*)d_in[0];
    const float* w1  = (const float*)d_in[1];
    const float* w2  = (const float*)d_in[2];
    const float* b2  = (const float*)d_in[3];
    const float* ls  = (const float*)d_in[4];
    float* out = (float*)d_out;
    float* h   = (float*)d_ws;   // B*SH*H*W floats = 9.4 MB

    dim3 blk(256);
    dim3 g1(WW / AX, HH / AY, BB);
    conv1_gelu_kernel<<<g1, blk, 0, stream>>>(x, w1, h);

    dim3 g2(WW / 16, HH / 16, BB * CC);
    coeff_sample_kernel<<<g2, blk, 0, stream>>>(x, h, w2, b2, ls, out);
}

// Round 5
// 329.069 us; speedup vs baseline: 1.0700x; 1.0420x over previous
//
#include <hip/hip_runtime.h>

#define HH 192
#define WW 192
#define CC 64
#define BB 8
#define SH 8
#define HWSZ (HH*WW)
#define TAU 0.1f

// ======== Kernel A1: conv3x3 partial sums over 16-channel groups ========
// 32x16 output tile, 256 threads, 2 px/thread, channels staged 8-at-a-time in LDS.
// Partials (G groups) land in d_out (scratch until kernel B overwrites it).
#define AX 32
#define AY 16
#define HALOX 34
#define HALOY 18
#define PADX 37                 // odd pad -> <=2-way LDS aliasing (free)
#define CCH 8                   // channels per LDS round
#define G 4                     // channel groups (blocks per tile)
#define CPG (CC/G)              // 16 channels per group
#define PLANE_ELTS (HALOY*HALOX)   // 612
#define LDS_CSTRIDE (HALOY*PADX)   // 666

__global__ __launch_bounds__(256) void conv1_part_kernel(
    const float* __restrict__ x, const float* __restrict__ w1, float* __restrict__ partial)
{
    __shared__ float tile[CCH][HALOY][PADX];
    const int t  = threadIdx.x;
    const int bx = blockIdx.x * AX;
    const int by = blockIdx.y * AY;
    const int zz = blockIdx.z;
    const int b  = zz >> 2;
    const int g  = zz & (G - 1);

    // 3 round-invariant load slots over the 18x34 halo plane
    int  g_off[3], l_off[3];
    bool val[3], ok[3];
#pragma unroll
    for (int i = 0; i < 3; i++) {
        int idx = t + i * 256;
        bool v  = idx < PLANE_ELTS;
        int iy  = idx / HALOX;
        int ix  = idx - iy * HALOX;
        int gy  = by + iy - 1;
        int gx  = bx + ix - 1;
        bool o  = v && (gy >= 0) && (gy < HH) && (gx >= 0) && (gx < WW);
        val[i]  = v;
        ok[i]   = o;
        g_off[i] = o ? (gy * WW + gx) : 0;
        l_off[i] = iy * PADX + ix;
    }

    const int tx = t & 15, ty = t >> 4;
    const int ox = tx * 2, oy = ty;

    float acc[SH][2];
#pragma unroll
    for (int sh = 0; sh < SH; sh++) { acc[sh][0] = 0.f; acc[sh][1] = 0.f; }

    float* tile0 = &tile[0][0][0];
    const float* xp = x + ((size_t)(b * CC + g * CPG)) * HWSZ;

    for (int r = 0; r < CPG / CCH; r++) {
        const int cbase = r * CCH;
#pragma unroll
        for (int cl = 0; cl < CCH; cl++) {
            const float* xpc = xp + (size_t)(cbase + cl) * HWSZ;
#pragma unroll
            for (int i = 0; i < 3; i++) {
                float v = 0.f;
                if (ok[i]) v = xpc[g_off[i]];
                if (val[i]) tile0[cl * LDS_CSTRIDE + l_off[i]] = v;
            }
        }
        __syncthreads();

#pragma unroll
        for (int cl = 0; cl < CCH; cl++) {
            float win[3][4];
#pragma unroll
            for (int i = 0; i < 3; i++)
#pragma unroll
                for (int j = 0; j < 4; j++)
                    win[i][j] = tile[cl][oy + i][ox + j];

            const int c = g * CPG + cbase + cl;
#pragma unroll
            for (int sh = 0; sh < SH; sh++) {
                const float* ws = w1 + ((size_t)sh * CC + c) * 9;   // uniform -> s_load
                float a0 = acc[sh][0], a1 = acc[sh][1];
                a0 = fmaf(win[0][0], ws[0], a0); a1 = fmaf(win[0][1], ws[0], a1);
                a0 = fmaf(win[0][1], ws[1], a0); a1 = fmaf(win[0][2], ws[1], a1);
                a0 = fmaf(win[0][2], ws[2], a0); a1 = fmaf(win[0][3], ws[2], a1);
                a0 = fmaf(win[1][0], ws[3], a0); a1 = fmaf(win[1][1], ws[3], a1);
                a0 = fmaf(win[1][1], ws[4], a0); a1 = fmaf(win[1][2], ws[4], a1);
                a0 = fmaf(win[1][2], ws[5], a0); a1 = fmaf(win[1][3], ws[5], a1);
                a0 = fmaf(win[2][0], ws[6], a0); a1 = fmaf(win[2][1], ws[6], a1);
                a0 = fmaf(win[2][1], ws[7], a0); a1 = fmaf(win[2][2], ws[7], a1);
                a0 = fmaf(win[2][2], ws[8], a0); a1 = fmaf(win[2][3], ws[8], a1);
                acc[sh][0] = a0; acc[sh][1] = a1;
            }
        }
        __syncthreads();
    }

    const int y = by + oy, xo = bx + ox;
#pragma unroll
    for (int sh = 0; sh < SH; sh++) {
        float2 p; p.x = acc[sh][0]; p.y = acc[sh][1];
        *reinterpret_cast<float2*>(
            &partial[(((size_t)g * BB + b) * SH + sh) * HWSZ + y * WW + xo]) = p;
    }
}

// ======== Kernel A2: reduce G partials + exact GELU -> h ========
#define N4 (BB * SH * HWSZ / 4)      // 589824 float4s
#define GSTRIDE (BB * SH * HWSZ / 4) // float4 stride between groups

__global__ __launch_bounds__(256) void reduce_gelu_kernel(
    const float4* __restrict__ partial, float4* __restrict__ h)
{
    int i = blockIdx.x * 256 + threadIdx.x;
    if (i >= N4) return;
    float4 a = partial[i];
    float4 b = partial[i + GSTRIDE];
    float4 c = partial[i + 2 * GSTRIDE];
    float4 d = partial[i + 3 * GSTRIDE];
    float4 s;
    s.x = (a.x + b.x) + (c.x + d.x);
    s.y = (a.y + b.y) + (c.y + d.y);
    s.z = (a.z + b.z) + (c.z + d.z);
    s.w = (a.w + b.w) + (c.w + d.w);
    s.x = 0.5f * s.x * (1.f + erff(s.x * 0.70710678118654752f));
    s.y = 0.5f * s.y * (1.f + erff(s.y * 0.70710678118654752f));
    s.z = 0.5f * s.z * (1.f + erff(s.z * 0.70710678118654752f));
    s.w = 0.5f * s.w * (1.f + erff(s.w * 0.70710678118654752f));
    h[i] = s;
}

// ======== Kernel B: 1x1 conv coeffs + softplus/clip + 4 bilinear samples ========
__device__ __forceinline__ float sample_x(const float* __restrict__ img,
                                          int r0, int r1, float wy, float px)
{
    px = fminf(fmaxf(px, 0.f), 191.f);
    float x0f = floorf(px);
    float wx  = px - x0f;
    int x0 = (int)x0f;
    int x1 = x0 + ((x0 < WW - 1) ? 1 : 0);
    float v00 = img[r0 + x0], v01 = img[r0 + x1];
    float v10 = img[r1 + x0], v11 = img[r1 + x1];
    float top = fmaf(wx, v01 - v00, v00);
    float bot = fmaf(wx, v11 - v10, v10);
    return fmaf(wy, bot - top, top);
}

__device__ __forceinline__ float sample_y(const float* __restrict__ img,
                                          int x0, int x1, float wx, float py)
{
    py = fminf(fmaxf(py, 0.f), 191.f);
    float y0f = floorf(py);
    float wy  = py - y0f;
    int y0 = (int)y0f;
    int r0 = y0 * WW;
    int r1 = r0 + ((y0 < HH - 1) ? WW : 0);
    float v00 = img[r0 + x0], v01 = img[r0 + x1];
    float v10 = img[r1 + x0], v11 = img[r1 + x1];
    float top = fmaf(wx, v01 - v00, v00);
    float bot = fmaf(wx, v11 - v10, v10);
    return fmaf(wy, bot - top, top);
}

#define TILES_PER_PLANE 144   // 12x12 tiles of 16x16
#define NPLANES (BB*CC)       // 512

__global__ __launch_bounds__(256) void coeff_sample_kernel(
    const float* __restrict__ x, const float* __restrict__ hbuf,
    const float* __restrict__ w2, const float* __restrict__ b2,
    const float* __restrict__ log_scale, float* __restrict__ out)
{
    // XCD-aware swizzle: all 144 tiles of one (b,c) plane land on one XCD,
    // consecutively -> plane working set (~300KB) is L2-resident per XCD.
    const int li = blockIdx.x;
    const int rr = li & 7;
    const int m  = li >> 3;
    const int q  = m / TILES_PER_PLANE;
    const int tt = m - q * TILES_PER_PLANE;
    const int bc = (q << 3) | rr;          // plane id: b*64 + c
    const int tyb = tt / 12, txb = tt - tyb * 12;

    const int t  = threadIdx.x;
    const int tx = t & 15;
    const int ty = t >> 4;
    const int xo = txb * 16 + tx;
    const int y  = tyb * 16 + ty;
    const int c  = bc & 63;
    const int pix = y * WW + xo;

    const float* hp = hbuf + ((size_t)(bc >> 6) * SH) * HWSZ + pix;
    float hk[SH];
#pragma unroll
    for (int k = 0; k < SH; k++) hk[k] = hp[k * HWSZ];

    const int c4 = c * 4;
    float coeff[4];
#pragma unroll
    for (int j = 0; j < 4; j++) {
        const float* wr = w2 + (size_t)(c4 + j) * SH;  // uniform per block
        float s = b2[c4 + j];
#pragma unroll
        for (int k = 0; k < SH; k++) s = fmaf(hk[k], wr[k], s);
        coeff[j] = s;
    }

    // softplus (stable): max(z,0) + log(1+exp(-|z|))
    float z  = coeff[0];
    float a  = fmaxf(z, 0.f) + __logf(1.f + __expf(-fabsf(z)));
    float s  = __builtin_amdgcn_sqrtf(fmaf(a, TAU, 1e-8f));
    float dx = coeff[1] * TAU;
    float dy = coeff[2] * TAU;
    float cc = fminf(fmaxf(coeff[3], -5.f), 5.f);

    const float* img = x + (size_t)bc * HWSZ;
    const float px0 = (float)xo + dx * 95.5f;   // (W-1)/2 = 95.5
    const float py0 = (float)y  + dy * 95.5f;
    const float sp  = s * 95.5f;

    float u;
    {   // u_px + u_nx share the y interpolation state
        float py  = fminf(fmaxf(py0, 0.f), 191.f);
        float y0f = floorf(py);
        float wy  = py - y0f;
        int y0 = (int)y0f;
        int r0 = y0 * WW;
        int r1 = r0 + ((y0 < HH - 1) ? WW : 0);
        u = sample_x(img, r0, r1, wy, px0 + sp)
          + sample_x(img, r0, r1, wy, px0 - sp);
    }
    {   // u_py + u_ny share the x interpolation state
        float px  = fminf(fmaxf(px0, 0.f), 191.f);
        float x0f = floorf(px);
        float wx  = px - x0f;
        int x0 = (int)x0f;
        int x1 = x0 + ((x0 < WW - 1) ? 1 : 0);
        u += sample_y(img, x0, x1, wx, py0 + sp)
           + sample_y(img, x0, x1, wx, py0 - sp);
    }

    float xv    = img[pix];
    float scale = __expf(log_scale[0]);
    out[(size_t)bc * HWSZ + pix] = scale * fmaf(0.25f, u, TAU * cc * xv);
}

extern "C" void kernel_launch(void* const* d_in, const int* in_sizes, int n_in,
                              void* d_out, int out_size, void* d_ws, size_t ws_size,
                              hipStream_t stream)
{
    const float* x   = (const float*)d_in[0];
    const float* w1  = (const float*)d_in[1];
    const float* w2  = (const float*)d_in[2];
    const float* b2  = (const float*)d_in[3];
    const float* ls  = (const float*)d_in[4];
    float* out = (float*)d_out;
    float* h   = (float*)d_ws;        // B*SH*H*W floats = 9.4 MB
    float* part = out;                // d_out doubles as partial-sum scratch (G*B*SH*HW = 37.7MB)

    dim3 blk(256);
    dim3 g1(WW / AX, HH / AY, BB * G);
    conv1_part_kernel<<<g1, blk, 0, stream>>>(x, w1, part);

    reduce_gelu_kernel<<<dim3((N4 + 255) / 256), blk, 0, stream>>>(
        (const float4*)part, (float4*)h);

    coeff_sample_kernel<<<dim3(NPLANES * TILES_PER_PLANE), blk, 0, stream>>>(
        x, h, w2, b2, ls, out);
}

// Round 6
// 324.144 us; speedup vs baseline: 1.0862x; 1.0152x over previous
//
#include <hip/hip_runtime.h>

#define HH 192
#define WW 192
#define CC 64
#define BB 8
#define SH 8
#define HWSZ (HH*WW)
#define TAU 0.1f

// ======== Kernel A: conv3x3 (64->8, SAME) + exact GELU, h interleaved [b][pix][8] ========
// 16x16 tile, 256 threads, 1 px/thread, 8-channel LDS rounds, batched staging.
#define AT 16
#define HALO 18
#define PADX 20                       // even pad: b64-friendly, <=2-way bank aliasing
#define CCH 8
#define PLANE (HALO*HALO)             // 324
#define NELTS (CCH*PLANE)             // 2592
#define NSLOT 11                      // ceil(2592/256)
#define LDS_C (HALO*PADX)             // 360

__global__ __launch_bounds__(256) void conv1_gelu_kernel(
    const float* __restrict__ x, const float* __restrict__ w1, float* __restrict__ h)
{
    __shared__ float tile[CCH][HALO][PADX];     // 11.5 KB
    const int t  = threadIdx.x;
    const int bx = blockIdx.x * AT;
    const int by = blockIdx.y * AT;
    const int b  = blockIdx.z;

    // Round-invariant slot precompute: idx -> (cl, iy, ix); g_off includes cl*HWSZ.
    int g_off[NSLOT], l_off[NSLOT];
    bool ok[NSLOT];
#pragma unroll
    for (int i = 0; i < NSLOT; i++) {
        int idx = t + i * 256;
        bool v  = idx < NELTS;
        int cl  = idx / PLANE;
        int rem = idx - cl * PLANE;
        int iy  = rem / HALO;
        int ix  = rem - iy * HALO;
        int gy  = by + iy - 1;
        int gx  = bx + ix - 1;
        bool o  = v && (gy >= 0) && (gy < HH) && (gx >= 0) && (gx < WW);
        ok[i]    = o;
        g_off[i] = o ? (cl * HWSZ + gy * WW + gx) : 0;   // OOB -> safe addr 0
        l_off[i] = cl * LDS_C + iy * PADX + ix;
    }

    const int tx = t & 15, ty = t >> 4;

    float acc[SH];
#pragma unroll
    for (int sh = 0; sh < SH; sh++) acc[sh] = 0.f;

    float* tile0 = &tile[0][0][0];

    for (int r = 0; r < CC / CCH; r++) {
        const float* xp = x + ((size_t)(b * CC + r * CCH)) * HWSZ;

        // batched loads: all issued unconditionally (indep), then zero-select
        float vals[NSLOT];
#pragma unroll
        for (int i = 0; i < NSLOT; i++) vals[i] = xp[g_off[i]];
#pragma unroll
        for (int i = 0; i < NSLOT; i++) if (!ok[i]) vals[i] = 0.f;

        __syncthreads();   // previous round's reads done before overwrite
#pragma unroll
        for (int i = 0; i < NSLOT - 1; i++) tile0[l_off[i]] = vals[i];
        if (t < NELTS - (NSLOT - 1) * 256) tile0[l_off[NSLOT - 1]] = vals[NSLOT - 1];
        __syncthreads();

#pragma unroll
        for (int cl = 0; cl < CCH; cl++) {
            float win[3][3];
#pragma unroll
            for (int i = 0; i < 3; i++)
#pragma unroll
                for (int j = 0; j < 3; j++)
                    win[i][j] = tile[cl][ty + i][tx + j];

            const int c = r * CCH + cl;
#pragma unroll
            for (int sh = 0; sh < SH; sh++) {
                const float* ws = w1 + ((size_t)sh * CC + c) * 9;   // uniform -> s_load
                float a = acc[sh];
                a = fmaf(win[0][0], ws[0], a);
                a = fmaf(win[0][1], ws[1], a);
                a = fmaf(win[0][2], ws[2], a);
                a = fmaf(win[1][0], ws[3], a);
                a = fmaf(win[1][1], ws[4], a);
                a = fmaf(win[1][2], ws[5], a);
                a = fmaf(win[2][0], ws[6], a);
                a = fmaf(win[2][1], ws[7], a);
                a = fmaf(win[2][2], ws[8], a);
                acc[sh] = a;
            }
        }
    }

    // epilogue: exact GELU, store interleaved h[b][pix][8] as 2x float4
    const int pix = (by + ty) * WW + (bx + tx);
    float4 o0, o1;
    float g[SH];
#pragma unroll
    for (int sh = 0; sh < SH; sh++)
        g[sh] = 0.5f * acc[sh] * (1.f + erff(acc[sh] * 0.70710678118654752f));
    o0.x = g[0]; o0.y = g[1]; o0.z = g[2]; o0.w = g[3];
    o1.x = g[4]; o1.y = g[5]; o1.z = g[6]; o1.w = g[7];
    float4* hp = (float4*)&h[((size_t)b * HWSZ + pix) * SH];
    hp[0] = o0;
    hp[1] = o1;
}

// ======== Kernel B: 1x1 conv coeffs + softplus/clip + 4 bilinear samples ========
__device__ __forceinline__ float sample_x(const float* __restrict__ img,
                                          int r0, int r1, float wy, float px)
{
    px = fminf(fmaxf(px, 0.f), 191.f);
    float x0f = floorf(px);
    float wx  = px - x0f;
    int x0 = (int)x0f;
    int x1 = x0 + ((x0 < WW - 1) ? 1 : 0);
    float v00 = img[r0 + x0], v01 = img[r0 + x1];
    float v10 = img[r1 + x0], v11 = img[r1 + x1];
    float top = fmaf(wx, v01 - v00, v00);
    float bot = fmaf(wx, v11 - v10, v10);
    return fmaf(wy, bot - top, top);
}

__device__ __forceinline__ float sample_y(const float* __restrict__ img,
                                          int x0, int x1, float wx, float py)
{
    py = fminf(fmaxf(py, 0.f), 191.f);
    float y0f = floorf(py);
    float wy  = py - y0f;
    int y0 = (int)y0f;
    int r0 = y0 * WW;
    int r1 = r0 + ((y0 < HH - 1) ? WW : 0);
    float v00 = img[r0 + x0], v01 = img[r0 + x1];
    float v10 = img[r1 + x0], v11 = img[r1 + x1];
    float top = fmaf(wx, v01 - v00, v00);
    float bot = fmaf(wx, v11 - v10, v10);
    return fmaf(wy, bot - top, top);
}

#define TILES_PER_PLANE 144   // 12x12 tiles of 16x16
#define NPLANES (BB*CC)       // 512

__global__ __launch_bounds__(256) void coeff_sample_kernel(
    const float* __restrict__ x, const float* __restrict__ hbuf,
    const float* __restrict__ w2, const float* __restrict__ b2,
    const float* __restrict__ log_scale, float* __restrict__ out)
{
    // XCD-aware swizzle: all 144 tiles of one (b,c) plane land on one XCD.
    const int li = blockIdx.x;
    const int rr = li & 7;
    const int m  = li >> 3;
    const int q  = m / TILES_PER_PLANE;
    const int tt = m - q * TILES_PER_PLANE;
    const int bc = (q << 3) | rr;          // plane id: b*64 + c
    const int tyb = tt / 12, txb = tt - tyb * 12;

    const int t  = threadIdx.x;
    const int tx = t & 15;
    const int ty = t >> 4;
    const int xo = txb * 16 + tx;
    const int y  = tyb * 16 + ty;
    const int c  = bc & 63;
    const int pix = y * WW + xo;

    // h interleaved [b][pix][8]: two float4 loads
    const float4* hp4 = (const float4*)&hbuf[((size_t)(bc >> 6) * HWSZ + pix) * SH];
    float4 h0 = hp4[0], h1 = hp4[1];
    float hk[SH] = {h0.x, h0.y, h0.z, h0.w, h1.x, h1.y, h1.z, h1.w};

    const int c4 = c * 4;
    float coeff[4];
#pragma unroll
    for (int j = 0; j < 4; j++) {
        const float* wr = w2 + (size_t)(c4 + j) * SH;  // uniform per block
        float s = b2[c4 + j];
#pragma unroll
        for (int k = 0; k < SH; k++) s = fmaf(hk[k], wr[k], s);
        coeff[j] = s;
    }

    // softplus (stable): max(z,0) + log(1+exp(-|z|))
    float z  = coeff[0];
    float a  = fmaxf(z, 0.f) + __logf(1.f + __expf(-fabsf(z)));
    float s  = __builtin_amdgcn_sqrtf(fmaf(a, TAU, 1e-8f));
    float dx = coeff[1] * TAU;
    float dy = coeff[2] * TAU;
    float cc = fminf(fmaxf(coeff[3], -5.f), 5.f);

    const float* img = x + (size_t)bc * HWSZ;
    const float px0 = (float)xo + dx * 95.5f;   // (W-1)/2 = 95.5
    const float py0 = (float)y  + dy * 95.5f;
    const float sp  = s * 95.5f;

    float u;
    {   // u_px + u_nx share the y interpolation state
        float py  = fminf(fmaxf(py0, 0.f), 191.f);
        float y0f = floorf(py);
        float wy  = py - y0f;
        int y0 = (int)y0f;
        int r0 = y0 * WW;
        int r1 = r0 + ((y0 < HH - 1) ? WW : 0);
        u = sample_x(img, r0, r1, wy, px0 + sp)
          + sample_x(img, r0, r1, wy, px0 - sp);
    }
    {   // u_py + u_ny share the x interpolation state
        float px  = fminf(fmaxf(px0, 0.f), 191.f);
        float x0f = floorf(px);
        float wx  = px - x0f;
        int x0 = (int)x0f;
        int x1 = x0 + ((x0 < WW - 1) ? 1 : 0);
        u += sample_y(img, x0, x1, wx, py0 + sp)
           + sample_y(img, x0, x1, wx, py0 - sp);
    }

    float xv    = img[pix];
    float scale = __expf(log_scale[0]);
    out[(size_t)bc * HWSZ + pix] = scale * fmaf(0.25f, u, TAU * cc * xv);
}

extern "C" void kernel_launch(void* const* d_in, const int* in_sizes, int n_in,
                              void* d_out, int out_size, void* d_ws, size_t ws_size,
                              hipStream_t stream)
{
    const float* x   = (const float*)d_in[0];
    const float* w1  = (const float*)d_in[1];
    const float* w2  = (const float*)d_in[2];
    const float* b2  = (const float*)d_in[3];
    const float* ls  = (const float*)d_in[4];
    float* out = (float*)d_out;
    float* h   = (float*)d_ws;        // B*HW*8 floats = 9.4 MB, interleaved [b][pix][8]

    dim3 blk(256);
    dim3 g1(WW / AT, HH / AT, BB);    // 12 x 12 x 8 = 1152 blocks
    conv1_gelu_kernel<<<g1, blk, 0, stream>>>(x, w1, h);

    coeff_sample_kernel<<<dim3(NPLANES * TILES_PER_PLANE), blk, 0, stream>>>(
        x, h, w2, b2, ls, out);
}